// Round 7
// baseline (124.937 us; speedup 1.0000x reference)
//
#include <hip/hip_runtime.h>
#include <hip/hip_bf16.h>

#define BN 8192
#define DK 512
#define PN 4096
#define GY 8
#define PPB 512            // protos per slice
#define CH 32              // protos per chunk == class size (sorted)
#define NCH 16             // chunks per slice; chunk nt = class gy*16+nt
#define STRIDE 520         // row stride in elems (1040 B) — R1-proven layout
#define BUFELE (CH * STRIDE)
#define SENT (-1.0e30f)
#define L2E 1.4426950408889634f
#define LN2 0.6931471805599453f

typedef __bf16 bf16x8 __attribute__((ext_vector_type(8)));
typedef __bf16 bf16x4 __attribute__((ext_vector_type(4)));
typedef float f32x4 __attribute__((ext_vector_type(4)));

__device__ __forceinline__ float ex2(float x) { return __builtin_amdgcn_exp2f(x); }

__device__ __forceinline__ void gl_lds16(const void* g, void* l) {
    __builtin_amdgcn_global_load_lds(
        (const __attribute__((address_space(1))) void*)g,
        (__attribute__((address_space(3))) void*)l, 16, 0, 0);
}

// ---------------------------------------------------------------------------
// K1: protos only — bf16 cast in CLASS-SORTED order + p_sq*log2e (sorted).
// Original proto p has class p%128; sorted row s = (p%128)*32 + p/128.
// ---------------------------------------------------------------------------
__global__ __launch_bounds__(256) void k_prep(const float* __restrict__ proto,
                                              __bf16* __restrict__ pB,
                                              float* __restrict__ p_sq) {
    int p  = blockIdx.x * 4 + (threadIdx.x >> 6);
    int ln = threadIdx.x & 63;
    const float* src = proto + (size_t)p * DK;
    float4 a = *(const float4*)(src + ln * 4);
    float4 b = *(const float4*)(src + 256 + ln * 4);
    float s = a.x * a.x + a.y * a.y + a.z * a.z + a.w * a.w
            + b.x * b.x + b.y * b.y + b.z * b.z + b.w * b.w;
#pragma unroll
    for (int m = 1; m < 64; m <<= 1) s += __shfl_xor(s, m, 64);
    int sidx = (p & 127) * 32 + (p >> 7);
    bf16x4 c0, c1;
    c0[0] = (__bf16)a.x; c0[1] = (__bf16)a.y; c0[2] = (__bf16)a.z; c0[3] = (__bf16)a.w;
    c1[0] = (__bf16)b.x; c1[1] = (__bf16)b.y; c1[2] = (__bf16)b.z; c1[3] = (__bf16)b.w;
    *(bf16x4*)(pB + (size_t)sidx * DK + ln * 4) = c0;
    *(bf16x4*)(pB + (size_t)sidx * DK + 256 + ln * 4) = c1;
    if (ln == 0) p_sq[sidx] = s * L2E;
}

// ---------------------------------------------------------------------------
// K2: R1's verified fused GEMM + online-LSE (A resident 32 rows/wave, B
// double-buffered via global_load_lds, STRIDE 520 linear — swizzle reverted,
// conflicts proven write-side/inherent). New in R7:
//  * dual accumulator ping-pong: chunk nt-1's LSE (DEN at even ks, NUM
//    select-form at odd ks) is computed from its still-live accumulator
//    INSIDE chunk nt's MFMA loop; z recomputed inline -> no zp regs, no
//    tail z-write. Chunk loop unrolled x2 for static acc indexing.
//  * numerator is branch-free (select); per-chunk tail = barrier only.
//  * A-frags loaded directly global->reg (f32->bf16 in reg): no A LDS
//    round-trip, no 8 prologue barriers.
// Chunk -1 pseudo-fold: accB=0 + npsP=SENT gives z=SENT; Sd pollution
// self-cleans on first real rescale (ex2(SENT-real)=0). clsp=-1 -> no hit.
// ---------------------------------------------------------------------------
__global__ __launch_bounds__(256, 2) void k_main(
        const float* __restrict__ feat,
        const __bf16* __restrict__ pB,
        const float* __restrict__ p_sq,    // sorted, pre-scaled by log2(e)
        const int* __restrict__ label,
        float4* __restrict__ part) {

    __shared__ __bf16 sM[2 * BUFELE];      // 66,560 B (B double-buffer only)
    __shared__ float  sPsq[PPB];           // 2 KB

    const int t    = threadIdx.x;
    const int w    = t >> 6;
    const int l    = t & 63;
    const int ln   = l & 15;
    const int quad = l >> 4;
    const int bx   = blockIdx.x;
    const int gy   = blockIdx.y;
    const int rw   = bx * 128 + w * 32;
    const int p0   = gy * PPB;

    // issue chunk c: wave stages rows w*8..w*8+7 (wave-uniform LDS base)
#define ISSUE(c) {                                                          \
        const __bf16* g = pB + (size_t)(p0 + (c) * CH + w * 8) * DK + l * 8; \
        __bf16* lp = sM + ((c) & 1) * BUFELE + (w * 8) * STRIDE;            \
        _Pragma("unroll")                                                   \
        for (int j = 0; j < 8; ++j)                                         \
            gl_lds16(g + j * DK, lp + j * STRIDE);                          \
    }

    // ---- chunk-0 prefetch FIRST (lands during A-frag loading) ----
    ISSUE(0);
    sPsq[t]       = p_sq[p0 + t];
    sPsq[t + 256] = p_sq[p0 + t + 256];

    int lab[2][4];
#pragma unroll
    for (int mf = 0; mf < 2; ++mf)
#pragma unroll
        for (int r = 0; r < 4; ++r)
            lab[mf][r] = label[rw + mf * 16 + quad * 4 + r];

    // ---- A-frags DIRECT from global (f32 -> bf16 in reg), 128 regs ----
    bf16x8 afrag[2][16];
#pragma unroll
    for (int mf = 0; mf < 2; ++mf) {
        const float* ar = feat + (size_t)(rw + mf * 16 + ln) * DK + quad * 8;
#pragma unroll
        for (int ks = 0; ks < 16; ++ks) {
            float4 u = *(const float4*)(ar + ks * 32);
            float4 v = *(const float4*)(ar + ks * 32 + 4);
            bf16x8 c;
            c[0] = (__bf16)u.x; c[1] = (__bf16)u.y; c[2] = (__bf16)u.z; c[3] = (__bf16)u.w;
            c[4] = (__bf16)v.x; c[5] = (__bf16)v.y; c[6] = (__bf16)v.z; c[7] = (__bf16)v.w;
            afrag[mf][ks] = c;
        }
    }

    __syncthreads();                       // sPsq visible + chunk 0 landed (all waves)

    // ---- online state (log2 domain) ----
    float Md[2][4], Sd[2][4], Mn[2][4], Sn[2][4];
#pragma unroll
    for (int mf = 0; mf < 2; ++mf)
#pragma unroll
        for (int r = 0; r < 4; ++r) {
            Md[mf][r] = SENT; Sd[mf][r] = 0.f;
            Mn[mf][r] = SENT; Sn[mf][r] = 0.f;
        }
    f32x4 accA[2][2], accB[2][2];
#pragma unroll
    for (int mf = 0; mf < 2; ++mf)
#pragma unroll
        for (int nf = 0; nf < 2; ++nf) {
            accA[mf][nf] = (f32x4){0.f, 0.f, 0.f, 0.f};
            accB[mf][nf] = (f32x4){0.f, 0.f, 0.f, 0.f};
        }
    float npsP0 = SENT, npsP1 = SENT;      // pseudo chunk -1
    int   clsp  = -1;

    // one chunk: accumulate CUR, fold PRV's LSE inside the MFMA loop
#define STEP(nt, CUR, PRV) {                                                \
        if ((nt) + 1 < NCH) ISSUE((nt) + 1);                                \
        const __bf16* sB = sM + ((nt) & 1) * BUFELE;                        \
        float nps0 = -sPsq[(nt) * 32 + ln];                                 \
        float nps1 = -sPsq[(nt) * 32 + 16 + ln];                            \
        _Pragma("unroll")                                                   \
        for (int mf = 0; mf < 2; ++mf)                                      \
        { _Pragma("unroll")                                                 \
          for (int nf = 0; nf < 2; ++nf)                                    \
            CUR[mf][nf] = (f32x4){0.f, 0.f, 0.f, 0.f}; }                    \
        _Pragma("unroll")                                                   \
        for (int ks = 0; ks < 16; ++ks) {                                   \
            bf16x8 b0 = *(const bf16x8*)(sB + ln * STRIDE + ks * 32 + quad * 8); \
            bf16x8 b1 = *(const bf16x8*)(sB + (16 + ln) * STRIDE + ks * 32 + quad * 8); \
            CUR[0][0] = __builtin_amdgcn_mfma_f32_16x16x32_bf16(afrag[0][ks], b0, CUR[0][0], 0, 0, 0); \
            CUR[0][1] = __builtin_amdgcn_mfma_f32_16x16x32_bf16(afrag[0][ks], b1, CUR[0][1], 0, 0, 0); \
            CUR[1][0] = __builtin_amdgcn_mfma_f32_16x16x32_bf16(afrag[1][ks], b0, CUR[1][0], 0, 0, 0); \
            CUR[1][1] = __builtin_amdgcn_mfma_f32_16x16x32_bf16(afrag[1][ks], b1, CUR[1][1], 0, 0, 0); \
            {                                                               \
                const int j  = ks >> 1;                                     \
                const int mf = j >> 2;                                      \
                const int r  = j & 3;                                       \
                float z0 = fmaf(PRV[mf][0][r], 2.0f * L2E, npsP0);          \
                float z1 = fmaf(PRV[mf][1][r], 2.0f * L2E, npsP1);          \
                if ((ks & 1) == 0) {            /* DEN slice j */           \
                    float nm = fmaxf(Md[mf][r], fmaxf(z0, z1));             \
                    float e  = ex2(z0 - nm) + ex2(z1 - nm);                 \
                    Sd[mf][r] = fmaf(Sd[mf][r], ex2(Md[mf][r] - nm), e);    \
                    Md[mf][r] = nm;                                         \
                } else {                        /* NUM slice j, select */   \
                    bool hit  = (clsp == lab[mf][r]);                       \
                    float mn2 = fmaxf(z0, z1);                              \
                    float e2  = ex2(z0 - mn2) + ex2(z1 - mn2);              \
                    Mn[mf][r] = hit ? mn2 : Mn[mf][r];                      \
                    Sn[mf][r] = hit ? e2  : Sn[mf][r];                      \
                }                                                           \
            }                                                               \
        }                                                                   \
        npsP0 = nps0; npsP1 = nps1;                                         \
        clsp  = gy * 16 + (nt);                                             \
        __syncthreads();                                                    \
    }

#pragma unroll 1
    for (int nt2 = 0; nt2 < NCH / 2; ++nt2) {
        STEP(2 * nt2,     accA, accB);
        STEP(2 * nt2 + 1, accB, accA);
    }

    // ---- epilogue: fold the last chunk (held in accB) ----
#pragma unroll
    for (int j = 0; j < 8; ++j) {
        const int mf = j >> 2, r = j & 3;
        float z0 = fmaf(accB[mf][0][r], 2.0f * L2E, npsP0);
        float z1 = fmaf(accB[mf][1][r], 2.0f * L2E, npsP1);
        float nm = fmaxf(Md[mf][r], fmaxf(z0, z1));
        float e  = ex2(z0 - nm) + ex2(z1 - nm);
        Sd[mf][r] = fmaf(Sd[mf][r], ex2(Md[mf][r] - nm), e);
        Md[mf][r] = nm;
        bool hit  = (clsp == lab[mf][r]);
        float mn2 = fmaxf(z0, z1);
        float e2  = ex2(z0 - mn2) + ex2(z1 - mn2);
        Mn[mf][r] = hit ? mn2 : Mn[mf][r];
        Sn[mf][r] = hit ? e2  : Sn[mf][r];
    }

#undef STEP
#undef ISSUE

    // ---- merge 16 lanes per quad-group, write partials ----
#pragma unroll
    for (int mf = 0; mf < 2; ++mf)
#pragma unroll
        for (int r = 0; r < 4; ++r) {
            float md = Md[mf][r], sd = Sd[mf][r];
            float mn = Mn[mf][r], sn = Sn[mf][r];
#pragma unroll
            for (int m = 1; m < 16; m <<= 1) {
                float omd = __shfl_xor(md, m, 64);
                float osd = __shfl_xor(sd, m, 64);
                float omn = __shfl_xor(mn, m, 64);
                float osn = __shfl_xor(sn, m, 64);
                float nm = fmaxf(md, omd);
                sd = sd * ex2(md - nm) + osd * ex2(omd - nm);
                md = nm;
                nm = fmaxf(mn, omn);
                sn = sn * ex2(mn - nm) + osn * ex2(omn - nm);
                mn = nm;
            }
            if (ln == 0) {
                int row = rw + mf * 16 + quad * 4 + r;
                part[row * GY + gy] = make_float4(md, sd, mn, sn);
            }
        }
}

// ---------------------------------------------------------------------------
// K3: wave-parallel partial merge — one lane per (row, gy) partial,
// coalesced float4 loads, 3-step shuffle reduce across 8 lanes per row.
// ---------------------------------------------------------------------------
__global__ __launch_bounds__(256) void k_comb(const float4* __restrict__ part,
                                              float* __restrict__ out) {
    int t   = threadIdx.x;
    int w   = t >> 6;
    int l   = t & 63;
    int row = blockIdx.x * 32 + w * 8 + (l >> 3);
    int q   = l & 7;
    float4 v = part[row * GY + q];
    float md = v.x, sd = v.y, mn = v.z, sn = v.w;
#pragma unroll
    for (int m = 1; m < 8; m <<= 1) {
        float omd = __shfl_xor(md, m, 64);
        float osd = __shfl_xor(sd, m, 64);
        float omn = __shfl_xor(mn, m, 64);
        float osn = __shfl_xor(sn, m, 64);
        float nm = fmaxf(md, omd);
        sd = sd * ex2(md - nm) + osd * ex2(omd - nm);
        md = nm;
        nm = fmaxf(mn, omn);
        sn = sn * ex2(mn - nm) + osn * ex2(omn - nm);
        mn = nm;
    }
    if (q == 0)
        out[row] = ((md + __builtin_amdgcn_logf(sd)) - (mn + __builtin_amdgcn_logf(sn))) * LN2;
}

extern "C" void kernel_launch(void* const* d_in, const int* in_sizes, int n_in,
                              void* d_out, int out_size, void* d_ws, size_t ws_size,
                              hipStream_t stream) {
    const float* feat   = (const float*)d_in[0];
    const int*   label  = (const int*)d_in[1];
    const float* proto  = (const float*)d_in[2];
    float*       out    = (float*)d_out;

    char* w = (char*)d_ws;
    __bf16* pB    = (__bf16*)(w);                 // 4096*512*2  = 4,194,304 B
    float*  p_sq  = (float*)(w + 4194304);        // 4096*4
    float4* part  = (float4*)(w + 4243456);       // 8192*GY*16

    hipLaunchKernelGGL(k_prep, dim3(PN / 4), dim3(256), 0, stream,
                       proto, pB, p_sq);
    hipLaunchKernelGGL(k_main, dim3(64, GY), dim3(256), 0, stream,
                       feat, pB, p_sq, label, part);
    hipLaunchKernelGGL(k_comb, dim3(BN / 32), dim3(256), 0, stream,
                       part, out);
}